// Round 12
// baseline (4941.441 us; speedup 1.0000x reference)
//
#include <hip/hip_runtime.h>

// Shapes (fixed): B=4, L=64, E=8, Q=16, K=32, H=512, NH=8, HD=64
// ROOT CAUSE (found R11): Output 0 = out[4,64,8,16,512] = 16,777,216 elements, but
// rounds 0-11 used a mis-multiplied 8,388,608 for the top_attn offset -> top writes
// landed in the middle of Output 0, clobbering blocks ble in [1024,1152). All error
// signatures (0.2153 unneg / 0.3887 neg = 2*refmax / R9-R10 stat corruption) fit.
// Fix: top = out + 16777216. Kernel = R4 fused (wiring proven dict-order by R8).
//
// LDS (dynamic, 147456 B): region0 [0,49152): qinh[16][256]@0; kinh/vinh[32][256]@16384;
//   s[8][16][32]@0 (after projections). region1: qp[16][512]@49152; kp[32][512]@81920 (swz);
//   vp[32][512]@49152 (after scores, swz); x[16][512]@114688.
// kp/vp column-XOR-swizzled by ((row&7)<<2) to break 32-way bank conflicts.

#define THREADS 512

__global__ __launch_bounds__(THREADS) void fused_attn(
    const float* __restrict__ query, const float* __restrict__ key_ant,
    const float* __restrict__ value_ant, const float* __restrict__ bias,
    const float* __restrict__ Wq, const float* __restrict__ bq,
    const float* __restrict__ Wk, const float* __restrict__ bk,
    const float* __restrict__ Wv, const float* __restrict__ bv,
    const float* __restrict__ Wo, const float* __restrict__ bo,
    float* __restrict__ out, float* __restrict__ top) {
  extern __shared__ char smem[];
  float* qinh = (float*)(smem);           // [16][256]
  float* kinh = (float*)(smem + 16384);   // [32][256] (also vinh)
  float* s    = (float*)(smem);           // [8][16][32] flat 4096 (after projections)
  float* qp   = (float*)(smem + 49152);   // [16][512]
  float* kp   = (float*)(smem + 81920);   // [32][512] swizzled
  float* vp   = (float*)(smem + 49152);   // [32][512] swizzled (after scores)
  float* x    = (float*)(smem + 114688);  // [16][512]

  const int t = threadIdx.x;
  const int ble = blockIdx.x;
  const int e = ble & 7, bl = ble >> 3;
  const float* QIN = query + (size_t)ble * 16 * 512;
  const float* KIN = key_ant + (size_t)ble * 32 * 512;
  const float* VIN = value_ant + (size_t)ble * 32 * 512;

  // ---------------- proj Q: qp = (QIN @ Wq + bq) * 0.125 ----------------
  {
    float acc[16];
#pragma unroll
    for (int w = 0; w < 16; ++w) acc[w] = 0.f;
    for (int half = 0; half < 2; ++half) {
      for (int i = t; i < 4096; i += THREADS) {
        int w = i >> 8, h = i & 255;
        qinh[i] = QIN[w * 512 + half * 256 + h];
      }
      __syncthreads();
      for (int h0 = 0; h0 < 256; h0 += 8) {
        float wr[8];
#pragma unroll
        for (int r = 0; r < 8; ++r) wr[r] = Wq[(size_t)(half * 256 + h0 + r) * 512 + t];
#pragma unroll
        for (int r = 0; r < 8; ++r)
#pragma unroll
          for (int w = 0; w < 16; ++w)
            acc[w] = fmaf(qinh[w * 256 + h0 + r], wr[r], acc[w]);
      }
      __syncthreads();
    }
    float bqv = bq[t];
#pragma unroll
    for (int w = 0; w < 16; ++w) qp[w * 512 + t] = (acc[w] + bqv) * 0.125f;
  }

  // ---------------- proj K: kp = KIN @ Wk + bk (swizzled store) ----------------
  {
    float acc[32];
#pragma unroll
    for (int w = 0; w < 32; ++w) acc[w] = 0.f;
    for (int half = 0; half < 2; ++half) {
      for (int i = t; i < 8192; i += THREADS) {
        int w = i >> 8, h = i & 255;
        kinh[i] = KIN[w * 512 + half * 256 + h];
      }
      __syncthreads();
      for (int h0 = 0; h0 < 256; h0 += 8) {
        float wr[8];
#pragma unroll
        for (int r = 0; r < 8; ++r) wr[r] = Wk[(size_t)(half * 256 + h0 + r) * 512 + t];
#pragma unroll
        for (int r = 0; r < 8; ++r)
#pragma unroll
          for (int w = 0; w < 32; ++w)
            acc[w] = fmaf(kinh[w * 256 + h0 + r], wr[r], acc[w]);
      }
      __syncthreads();
    }
    float bkv = bk[t];
#pragma unroll
    for (int w = 0; w < 32; ++w) kp[w * 512 + (t ^ ((w & 7) << 2))] = acc[w] + bkv;
  }
  __syncthreads();

  // ------- scores: s[n][q][k] = qp[q][n*64+:64] . kp[k][n*64+:64] + bias -------
  for (int i = 0; i < 8; ++i) {
    int idx = t + i * THREADS;
    int n = idx >> 9, rem = idx & 511, q = rem >> 5, k = rem & 31;
    const float* qrow = qp + q * 512 + n * 64;
    const float* krow = kp + k * 512 + n * 64;
    int xo = (k & 7) << 2;
    float a = 0.f;
#pragma unroll
    for (int d = 0; d < 64; ++d) a = fmaf(qrow[d], krow[d ^ xo], a);
    s[idx] = a + bias[(size_t)ble * 512 + q * 32 + k];
  }
  __syncthreads();

  // ------- softmax rows (t<128 owns (n,q)) + top_attn raw-view slice -------
  if (t < 128) {
    int n = t >> 4, q = t & 15;
    float* row = s + n * 512 + q * 32;
    float mx = row[0];
#pragma unroll
    for (int k = 1; k < 32; ++k) mx = fmaxf(mx, row[k]);
    float sum = 0.f;
#pragma unroll
    for (int k = 0; k < 32; ++k) {
      float p = expf(row[k] - mx);
      row[k] = p;
      sum += p;
    }
    float inv = 1.f / sum;
#pragma unroll
    for (int k = 0; k < 32; ++k) row[k] *= inv;
    if (((n & 3) == 0) && q < 8) {  // only n in {0,4}, q<8 land in the sliced view
      int qp_ = 2 * e + (n >> 2);
#pragma unroll
      for (int k = 0; k < 32; ++k) {
        int kp_ = 4 * q + (k >> 3), ep_ = k & 7;
        top[(((size_t)bl * 16 + qp_) * 32 + kp_) * 8 + ep_] = row[k];
      }
    }
  }
  __syncthreads();

  // ------- proj V: vp = VIN @ Wv + bv (swizzled, overwrites qp/kp) -------
  {
    float acc[32];
#pragma unroll
    for (int w = 0; w < 32; ++w) acc[w] = 0.f;
    for (int half = 0; half < 2; ++half) {
      for (int i = t; i < 8192; i += THREADS) {
        int w = i >> 8, h = i & 255;
        kinh[i] = VIN[w * 512 + half * 256 + h];
      }
      __syncthreads();
      for (int h0 = 0; h0 < 256; h0 += 8) {
        float wr[8];
#pragma unroll
        for (int r = 0; r < 8; ++r) wr[r] = Wv[(size_t)(half * 256 + h0 + r) * 512 + t];
#pragma unroll
        for (int r = 0; r < 8; ++r)
#pragma unroll
          for (int w = 0; w < 32; ++w)
            acc[w] = fmaf(kinh[w * 256 + h0 + r], wr[r], acc[w]);
      }
      __syncthreads();
    }
    float bvv = bv[t];
#pragma unroll
    for (int w = 0; w < 32; ++w) vp[w * 512 + (t ^ ((w & 7) << 2))] = acc[w] + bvv;
  }
  __syncthreads();

  // ------- PV: x[q][j] = sum_k attn[n][q][k] * vp[k][j],  n = j>>6 -------
  {
    int j = t, n = j >> 6;
    float xa[16];
#pragma unroll
    for (int q = 0; q < 16; ++q) xa[q] = 0.f;
#pragma unroll
    for (int k = 0; k < 32; ++k) {
      float pv = vp[k * 512 + (j ^ ((k & 7) << 2))];
      const float* prow = s + n * 512 + k;
#pragma unroll
      for (int q = 0; q < 16; ++q) xa[q] = fmaf(prow[q * 32], pv, xa[q]);
    }
#pragma unroll
    for (int q = 0; q < 16; ++q) x[q * 512 + j] = xa[q];
  }
  __syncthreads();

  // ---------------- out proj: out = x @ Wo + bo ----------------
  {
    float acc[16];
#pragma unroll
    for (int w = 0; w < 16; ++w) acc[w] = 0.f;
    for (int h0 = 0; h0 < 512; h0 += 8) {
      float wr[8];
#pragma unroll
      for (int r = 0; r < 8; ++r) wr[r] = Wo[(size_t)(h0 + r) * 512 + t];
#pragma unroll
      for (int r = 0; r < 8; ++r)
#pragma unroll
        for (int w = 0; w < 16; ++w)
          acc[w] = fmaf(x[w * 512 + h0 + r], wr[r], acc[w]);
    }
    float bov = bo[t];
#pragma unroll
    for (int w = 0; w < 16; ++w)
      out[((size_t)ble * 16 + w) * 512 + t] = acc[w] + bov;
  }
}

extern "C" void kernel_launch(void* const* d_in, const int* in_sizes, int n_in,
                              void* d_out, int out_size, void* d_ws, size_t ws_size,
                              hipStream_t stream) {
  const float* query = (const float*)d_in[0];
  const float* key_a = (const float*)d_in[1];
  const float* val_a = (const float*)d_in[2];
  const float* bias  = (const float*)d_in[3];
  const float* Wq = (const float*)d_in[4];
  const float* bq = (const float*)d_in[5];
  const float* Wk = (const float*)d_in[6];
  const float* bk = (const float*)d_in[7];
  const float* Wv = (const float*)d_in[8];
  const float* bv = (const float*)d_in[9];
  const float* Wo = (const float*)d_in[10];
  const float* bo = (const float*)d_in[11];
  float* out = (float*)d_out;
  float* top = out + 16777216;  // Output 0 = 16,777,216 elements (B*L*E*Q*H)

  fused_attn<<<2048, THREADS, 147456, stream>>>(query, key_a, val_a, bias, Wq, bq, Wk, bk,
                                                Wv, bv, Wo, bo, out, top);
}

// Round 13
// 636.753 us; speedup vs baseline: 7.7604x; 7.7604x over previous
//
#include <hip/hip_runtime.h>
#include <hip/hip_bf16.h>

// Shapes (fixed): B=4, L=64, E=8, Q=16, K=32, H=512, NH=8, HD=64
// R13: MFMA rewrite of the proven R12 fused kernel.
//  - prep_w: Wq/Wk/Wv/Wo f32[K][N] -> ws bf16 transposed wt[4][N][K] (2MB).
//  - fused_mfma: one block per ble, 8 waves = 8 heads = 8 N-slices of 64 cols.
//    All GEMMs via mfma_f32_16x16x32_bf16 (f32 accum). Wave-local attention.
//  - Fallback: if ws_size < 2MB, launch the proven R12 f32 kernel.
// LDS (134400 B): actS/x [32][520]bf16 @0 ; qp[16][520] @33280 ; kp[32][520] @49920 ;
//   vpT[512][40] @83200 ; p[8][16][40] @124160.  (strides give <=2-way bank aliasing)

#define THREADS 512

typedef __attribute__((ext_vector_type(8))) short short8v;
typedef __attribute__((ext_vector_type(4))) short short4v;
typedef __attribute__((ext_vector_type(4))) float f32x4;

__device__ __forceinline__ short bf16b(float f) {
  __hip_bfloat16 h = __float2bfloat16(f);
  return *reinterpret_cast<short*>(&h);
}

// ---- W prep: wt[mat][n][k] = bf16(W[k][n]) ----
__global__ __launch_bounds__(256) void prep_w(const float* __restrict__ Wq,
                                              const float* __restrict__ Wk,
                                              const float* __restrict__ Wv,
                                              const float* __restrict__ Wo,
                                              short* __restrict__ wt) {
  __shared__ float tile[32][33];
  const int mat = blockIdx.x >> 8;
  const int tix = blockIdx.x & 255;
  const int n0 = (tix & 15) * 32, k0 = (tix >> 4) * 32;
  const float* W = (mat == 0) ? Wq : (mat == 1) ? Wk : (mat == 2) ? Wv : Wo;
  const int tx = threadIdx.x & 31, ty = threadIdx.x >> 5;  // 32 x 8
#pragma unroll
  for (int i = 0; i < 4; ++i)
    tile[ty + 8 * i][tx] = W[(size_t)(k0 + ty + 8 * i) * 512 + n0 + tx];
  __syncthreads();
#pragma unroll
  for (int i = 0; i < 4; ++i) {
    int n = ty + 8 * i, k = tx;
    wt[((size_t)(mat * 512 + n0 + n) << 9) + k0 + k] = bf16b(tile[k][n]);
  }
}

// ---- fused MFMA kernel ----
__global__ __launch_bounds__(THREADS) void fused_mfma(
    const float* __restrict__ query, const float* __restrict__ key_ant,
    const float* __restrict__ value_ant, const float* __restrict__ bias,
    const float* __restrict__ bq, const float* __restrict__ bk,
    const float* __restrict__ bv, const float* __restrict__ bo,
    const short* __restrict__ wt, float* __restrict__ out, float* __restrict__ top) {
  extern __shared__ char smem[];
  const int t = threadIdx.x, lane = t & 63, w = t >> 6;
  const int ble = blockIdx.x, e = ble & 7, bl = ble >> 3;
  const int lr = lane & 15, lo = lane >> 4;  // in-tile row/col, k-octet
  const int nw = w * 64;                     // wave's N-slice base = head slice

  const float* QIN = query + (size_t)ble * 16 * 512;
  const float* KIN = key_ant + (size_t)ble * 32 * 512;
  const float* VIN = value_ant + (size_t)ble * 32 * 512;

  auto stage = [&](const float* src, int rows) {
    for (int i = t; i < rows * 128; i += THREADS) {
      int r = i >> 7, c4 = (i & 127) << 2;
      float4 v = *(const float4*)&src[r * 512 + c4];
      short4v s4 = {bf16b(v.x), bf16b(v.y), bf16b(v.z), bf16b(v.w)};
      *(short4v*)(smem + r * 1040 + c4 * 2) = s4;
    }
  };

  // ================= K projection -> kp[32][520] @49920 =================
  stage(KIN, 32);
  __syncthreads();
  {
    f32x4 acc[2][4] = {};
    for (int ks = 0; ks < 16; ++ks) {
      short8v a0 = *(const short8v*)(smem + lr * 1040 + ks * 64 + lo * 16);
      short8v a1 = *(const short8v*)(smem + (lr + 16) * 1040 + ks * 64 + lo * 16);
#pragma unroll
      for (int nt = 0; nt < 4; ++nt) {
        short8v b = *(const short8v*)(wt + ((size_t)(512 + nw + nt * 16 + lr) << 9) + ks * 32 + lo * 8);
        acc[0][nt] = __builtin_amdgcn_mfma_f32_16x16x32_bf16(a0, b, acc[0][nt], 0, 0, 0);
        acc[1][nt] = __builtin_amdgcn_mfma_f32_16x16x32_bf16(a1, b, acc[1][nt], 0, 0, 0);
      }
    }
#pragma unroll
    for (int nt = 0; nt < 4; ++nt) {
      int n = nw + nt * 16 + lr;
      float bb = bk[n];
#pragma unroll
      for (int mt = 0; mt < 2; ++mt)
#pragma unroll
        for (int r = 0; r < 4; ++r)
          *(short*)(smem + 49920 + (mt * 16 + lo * 4 + r) * 1040 + n * 2) =
              bf16b(acc[mt][nt][r] + bb);
    }
  }
  __syncthreads();

  // ================= V projection -> vpT[512][40] @83200 =================
  stage(VIN, 32);
  __syncthreads();
  {
    f32x4 acc[2][4] = {};
    for (int ks = 0; ks < 16; ++ks) {
      short8v a0 = *(const short8v*)(smem + lr * 1040 + ks * 64 + lo * 16);
      short8v a1 = *(const short8v*)(smem + (lr + 16) * 1040 + ks * 64 + lo * 16);
#pragma unroll
      for (int nt = 0; nt < 4; ++nt) {
        short8v b = *(const short8v*)(wt + ((size_t)(1024 + nw + nt * 16 + lr) << 9) + ks * 32 + lo * 8);
        acc[0][nt] = __builtin_amdgcn_mfma_f32_16x16x32_bf16(a0, b, acc[0][nt], 0, 0, 0);
        acc[1][nt] = __builtin_amdgcn_mfma_f32_16x16x32_bf16(a1, b, acc[1][nt], 0, 0, 0);
      }
    }
#pragma unroll
    for (int nt = 0; nt < 4; ++nt) {
      int n = nw + nt * 16 + lr;
      float bb = bv[n];
#pragma unroll
      for (int mt = 0; mt < 2; ++mt) {
        short4v pk = {bf16b(acc[mt][nt][0] + bb), bf16b(acc[mt][nt][1] + bb),
                      bf16b(acc[mt][nt][2] + bb), bf16b(acc[mt][nt][3] + bb)};
        *(short4v*)(smem + 83200 + n * 80 + (mt * 16 + lo * 4) * 2) = pk;
      }
    }
  }
  __syncthreads();

  // ================= Q projection -> qp[16][520] @33280 (x0.125) =================
  stage(QIN, 16);
  __syncthreads();
  {
    f32x4 acc[4] = {};
    for (int ks = 0; ks < 16; ++ks) {
      short8v a0 = *(const short8v*)(smem + lr * 1040 + ks * 64 + lo * 16);
#pragma unroll
      for (int nt = 0; nt < 4; ++nt) {
        short8v b = *(const short8v*)(wt + ((size_t)(nw + nt * 16 + lr) << 9) + ks * 32 + lo * 8);
        acc[nt] = __builtin_amdgcn_mfma_f32_16x16x32_bf16(a0, b, acc[nt], 0, 0, 0);
      }
    }
#pragma unroll
    for (int nt = 0; nt < 4; ++nt) {
      int n = nw + nt * 16 + lr;
      float bb = bq[n];
#pragma unroll
      for (int r = 0; r < 4; ++r)
        *(short*)(smem + 33280 + (lo * 4 + r) * 1040 + n * 2) = bf16b((acc[nt][r] + bb) * 0.125f);
    }
  }
  __syncthreads();  // all Q-GEMM actS reads done -> x region reusable

  // ======== scores + softmax (wave-local; head h = w; d-slice = [64w,64w+64)) ========
  float attn8[8];  // [kt*4+r]
  {
    f32x4 sc[2] = {};
#pragma unroll
    for (int ks = 0; ks < 2; ++ks) {
      short8v aq = *(const short8v*)(smem + 33280 + lr * 1040 + (nw + ks * 32 + lo * 8) * 2);
#pragma unroll
      for (int kt = 0; kt < 2; ++kt) {
        short8v b = *(const short8v*)(smem + 49920 + (lr + 16 * kt) * 1040 + (nw + ks * 32 + lo * 8) * 2);
        sc[kt] = __builtin_amdgcn_mfma_f32_16x16x32_bf16(aq, b, sc[kt], 0, 0, 0);
      }
    }
    const float* brow = bias + (size_t)ble * 512;
    float s8[8];
#pragma unroll
    for (int kt = 0; kt < 2; ++kt)
#pragma unroll
      for (int r = 0; r < 4; ++r)
        s8[kt * 4 + r] = sc[kt][r] + brow[(lo * 4 + r) * 32 + lr + 16 * kt];
#pragma unroll
    for (int r = 0; r < 4; ++r) {
      float mx = fmaxf(s8[r], s8[4 + r]);
#pragma unroll
      for (int off = 1; off < 16; off <<= 1) mx = fmaxf(mx, __shfl_xor(mx, off, 16));
      float p0 = expf(s8[r] - mx), p1 = expf(s8[4 + r] - mx);
      float sm = p0 + p1;
#pragma unroll
      for (int off = 1; off < 16; off <<= 1) sm += __shfl_xor(sm, off, 16);
      float inv = 1.f / sm;
      attn8[r] = p0 * inv;
      attn8[4 + r] = p1 * inv;
    }
    // p_lds[w][q][key] + top_attn raw-view slice (heads 0,4; q<8)
#pragma unroll
    for (int kt = 0; kt < 2; ++kt)
#pragma unroll
      for (int r = 0; r < 4; ++r) {
        int q = lo * 4 + r, key = lr + 16 * kt;
        *(short*)(smem + 124160 + w * 1280 + q * 80 + key * 2) = bf16b(attn8[kt * 4 + r]);
        if (((w & 3) == 0) && lo < 2)
          top[(((size_t)bl * 16 + 2 * e + (w >> 2)) * 32 + 4 * q + (key >> 3)) * 8 + (key & 7)] =
              attn8[kt * 4 + r];
      }
  }

  // ================= PV -> x[16][520] bf16 @0 (wave cols [64w,64w+64)) =================
  {
    f32x4 xacc[4] = {};
    short8v ap = *(const short8v*)(smem + 124160 + w * 1280 + lr * 80 + lo * 16);
#pragma unroll
    for (int nt = 0; nt < 4; ++nt) {
      short8v b = *(const short8v*)(smem + 83200 + (nw + nt * 16 + lr) * 80 + lo * 16);
      xacc[nt] = __builtin_amdgcn_mfma_f32_16x16x32_bf16(ap, b, xacc[nt], 0, 0, 0);
    }
#pragma unroll
    for (int nt = 0; nt < 4; ++nt)
#pragma unroll
      for (int r = 0; r < 4; ++r)
        *(short*)(smem + (lo * 4 + r) * 1040 + (nw + nt * 16 + lr) * 2) = bf16b(xacc[nt][r]);
  }
  __syncthreads();

  // ================= out proj: out = x @ Wo + bo (f32 global) =================
  {
    f32x4 oacc[4] = {};
    for (int ks = 0; ks < 16; ++ks) {
      short8v ax = *(const short8v*)(smem + lr * 1040 + ks * 64 + lo * 16);
#pragma unroll
      for (int nt = 0; nt < 4; ++nt) {
        short8v b = *(const short8v*)(wt + ((size_t)(1536 + nw + nt * 16 + lr) << 9) + ks * 32 + lo * 8);
        oacc[nt] = __builtin_amdgcn_mfma_f32_16x16x32_bf16(ax, b, oacc[nt], 0, 0, 0);
      }
    }
#pragma unroll
    for (int nt = 0; nt < 4; ++nt) {
      int n = nw + nt * 16 + lr;
      float bb = bo[n];
#pragma unroll
      for (int r = 0; r < 4; ++r)
        out[((size_t)ble * 16 + lo * 4 + r) * 512 + n] = oacc[nt][r] + bb;
    }
  }
}

// ================= fallback: proven R12 f32 kernel =================
__global__ __launch_bounds__(THREADS) void fused_attn(
    const float* __restrict__ query, const float* __restrict__ key_ant,
    const float* __restrict__ value_ant, const float* __restrict__ bias,
    const float* __restrict__ Wq, const float* __restrict__ bq,
    const float* __restrict__ Wk, const float* __restrict__ bk,
    const float* __restrict__ Wv, const float* __restrict__ bv,
    const float* __restrict__ Wo, const float* __restrict__ bo,
    float* __restrict__ out, float* __restrict__ top) {
  extern __shared__ char smem[];
  float* qinh = (float*)(smem);
  float* kinh = (float*)(smem + 16384);
  float* s = (float*)(smem);
  float* qp = (float*)(smem + 49152);
  float* kp = (float*)(smem + 81920);
  float* vp = (float*)(smem + 49152);
  float* x = (float*)(smem + 114688);
  const int t = threadIdx.x;
  const int ble = blockIdx.x;
  const int e = ble & 7, bl = ble >> 3;
  const float* QIN = query + (size_t)ble * 16 * 512;
  const float* KIN = key_ant + (size_t)ble * 32 * 512;
  const float* VIN = value_ant + (size_t)ble * 32 * 512;
  {
    float acc[16];
#pragma unroll
    for (int w = 0; w < 16; ++w) acc[w] = 0.f;
    for (int half = 0; half < 2; ++half) {
      for (int i = t; i < 4096; i += THREADS) {
        int w = i >> 8, h = i & 255;
        qinh[i] = QIN[w * 512 + half * 256 + h];
      }
      __syncthreads();
      for (int h0 = 0; h0 < 256; h0 += 8) {
        float wr[8];
#pragma unroll
        for (int r = 0; r < 8; ++r) wr[r] = Wq[(size_t)(half * 256 + h0 + r) * 512 + t];
#pragma unroll
        for (int r = 0; r < 8; ++r)
#pragma unroll
          for (int w = 0; w < 16; ++w) acc[w] = fmaf(qinh[w * 256 + h0 + r], wr[r], acc[w]);
      }
      __syncthreads();
    }
    float bqv = bq[t];
#pragma unroll
    for (int w = 0; w < 16; ++w) qp[w * 512 + t] = (acc[w] + bqv) * 0.125f;
  }
  {
    float acc[32];
#pragma unroll
    for (int w = 0; w < 32; ++w) acc[w] = 0.f;
    for (int half = 0; half < 2; ++half) {
      for (int i = t; i < 8192; i += THREADS) {
        int w = i >> 8, h = i & 255;
        kinh[i] = KIN[w * 512 + half * 256 + h];
      }
      __syncthreads();
      for (int h0 = 0; h0 < 256; h0 += 8) {
        float wr[8];
#pragma unroll
        for (int r = 0; r < 8; ++r) wr[r] = Wk[(size_t)(half * 256 + h0 + r) * 512 + t];
#pragma unroll
        for (int r = 0; r < 8; ++r)
#pragma unroll
          for (int w = 0; w < 32; ++w) acc[w] = fmaf(kinh[w * 256 + h0 + r], wr[r], acc[w]);
      }
      __syncthreads();
    }
    float bkv = bk[t];
#pragma unroll
    for (int w = 0; w < 32; ++w) kp[w * 512 + (t ^ ((w & 7) << 2))] = acc[w] + bkv;
  }
  __syncthreads();
  for (int i = 0; i < 8; ++i) {
    int idx = t + i * THREADS;
    int n = idx >> 9, rem = idx & 511, q = rem >> 5, k = rem & 31;
    const float* qrow = qp + q * 512 + n * 64;
    const float* krow = kp + k * 512 + n * 64;
    int xo = (k & 7) << 2;
    float a = 0.f;
#pragma unroll
    for (int d = 0; d < 64; ++d) a = fmaf(qrow[d], krow[d ^ xo], a);
    s[idx] = a + bias[(size_t)ble * 512 + q * 32 + k];
  }
  __syncthreads();
  if (t < 128) {
    int n = t >> 4, q = t & 15;
    float* row = s + n * 512 + q * 32;
    float mx = row[0];
#pragma unroll
    for (int k = 1; k < 32; ++k) mx = fmaxf(mx, row[k]);
    float sum = 0.f;
#pragma unroll
    for (int k = 0; k < 32; ++k) {
      float p = expf(row[k] - mx);
      row[k] = p;
      sum += p;
    }
    float inv = 1.f / sum;
#pragma unroll
    for (int k = 0; k < 32; ++k) row[k] *= inv;
    if (((n & 3) == 0) && q < 8) {
      int qp_ = 2 * e + (n >> 2);
#pragma unroll
      for (int k = 0; k < 32; ++k) {
        int kp_ = 4 * q + (k >> 3), ep_ = k & 7;
        top[(((size_t)bl * 16 + qp_) * 32 + kp_) * 8 + ep_] = row[k];
      }
    }
  }
  __syncthreads();
  {
    float acc[32];
#pragma unroll
    for (int w = 0; w < 32; ++w) acc[w] = 0.f;
    for (int half = 0; half < 2; ++half) {
      for (int i = t; i < 8192; i += THREADS) {
        int w = i >> 8, h = i & 255;
        kinh[i] = VIN[w * 512 + half * 256 + h];
      }
      __syncthreads();
      for (int h0 = 0; h0 < 256; h0 += 8) {
        float wr[8];
#pragma unroll
        for (int r = 0; r < 8; ++r) wr[r] = Wv[(size_t)(half * 256 + h0 + r) * 512 + t];
#pragma unroll
        for (int r = 0; r < 8; ++r)
#pragma unroll
          for (int w = 0; w < 32; ++w) acc[w] = fmaf(kinh[w * 256 + h0 + r], wr[r], acc[w]);
      }
      __syncthreads();
    }
    float bvv = bv[t];
#pragma unroll
    for (int w = 0; w < 32; ++w) vp[w * 512 + (t ^ ((w & 7) << 2))] = acc[w] + bvv;
  }
  __syncthreads();
  {
    int j = t, n = j >> 6;
    float xa[16];
#pragma unroll
    for (int q = 0; q < 16; ++q) xa[q] = 0.f;
#pragma unroll
    for (int k = 0; k < 32; ++k) {
      float pv = vp[k * 512 + (j ^ ((k & 7) << 2))];
      const float* prow = s + n * 512 + k;
#pragma unroll
      for (int q = 0; q < 16; ++q) xa[q] = fmaf(prow[q * 32], pv, xa[q]);
    }
#pragma unroll
    for (int q = 0; q < 16; ++q) x[q * 512 + j] = xa[q];
  }
  __syncthreads();
  {
    float acc[16];
#pragma unroll
    for (int w = 0; w < 16; ++w) acc[w] = 0.f;
    for (int h0 = 0; h0 < 512; h0 += 8) {
      float wr[8];
#pragma unroll
      for (int r = 0; r < 8; ++r) wr[r] = Wo[(size_t)(h0 + r) * 512 + t];
#pragma unroll
      for (int r = 0; r < 8; ++r)
#pragma unroll
        for (int w = 0; w < 16; ++w) acc[w] = fmaf(x[w * 512 + h0 + r], wr[r], acc[w]);
    }
    float bov = bo[t];
#pragma unroll
    for (int w = 0; w < 16; ++w) out[((size_t)ble * 16 + w) * 512 + t] = acc[w] + bov;
  }
}

extern "C" void kernel_launch(void* const* d_in, const int* in_sizes, int n_in,
                              void* d_out, int out_size, void* d_ws, size_t ws_size,
                              hipStream_t stream) {
  const float* query = (const float*)d_in[0];
  const float* key_a = (const float*)d_in[1];
  const float* val_a = (const float*)d_in[2];
  const float* bias = (const float*)d_in[3];
  const float* Wq = (const float*)d_in[4];
  const float* bq = (const float*)d_in[5];
  const float* Wk = (const float*)d_in[6];
  const float* bk = (const float*)d_in[7];
  const float* Wv = (const float*)d_in[8];
  const float* bv = (const float*)d_in[9];
  const float* Wo = (const float*)d_in[10];
  const float* bo = (const float*)d_in[11];
  float* out = (float*)d_out;
  float* top = out + 16777216;

  if (ws_size >= (size_t)(4 * 512 * 512 * sizeof(short))) {
    short* wt = (short*)d_ws;
    prep_w<<<1024, 256, 0, stream>>>(Wq, Wk, Wv, Wo, wt);
    fused_mfma<<<2048, THREADS, 134400, stream>>>(query, key_a, val_a, bias, bq, bk, bv, bo,
                                                  wt, out, top);
  } else {
    fused_attn<<<2048, THREADS, 147456, stream>>>(query, key_a, val_a, bias, Wq, bq, Wk, bk,
                                                  Wv, bv, Wo, bo, out, top);
  }
}

// Round 14
// 544.108 us; speedup vs baseline: 9.0817x; 1.1703x over previous
//
#include <hip/hip_runtime.h>
#include <hip/hip_bf16.h>

// Shapes (fixed): B=4, L=64, E=8, Q=16, K=32, H=512, NH=8, HD=64
// R14: R13 MFMA kernel + latency fixes (R13 diagnosis: VGPR=64 forced serial
// wt-load->wait(0)->mfma chains, ~2.8K cyc/ks-iter):
//  1) __launch_bounds__(512,2): LDS caps occupancy at 2 waves/SIMD anyway; free the
//     register allocator (~256 VGPR budget).
//  2) Explicit 2-deep double-buffered wt-fragment prefetch (named bufs, full unroll).
//  3) T14 async staging: V/Q/bias global loads issued a phase early, held in regs.
// Math identical to R13 (passed, absmax 9.77e-4).
// LDS (134400 B): actS/x[32][520]bf16 @0 ; qp[16][520] @33280 ; kp[32][520] @49920 ;
//   vpT[512][40] @83200 ; p[8][16][40] @124160.

#define THREADS 512

typedef __attribute__((ext_vector_type(8))) short short8v;
typedef __attribute__((ext_vector_type(4))) short short4v;
typedef __attribute__((ext_vector_type(4))) float f32x4;

__device__ __forceinline__ short bf16b(float f) {
  __hip_bfloat16 h = __float2bfloat16(f);
  return *reinterpret_cast<short*>(&h);
}

// ---- W prep: wt[mat][n][k] = bf16(W[k][n]) ----
__global__ __launch_bounds__(256) void prep_w(const float* __restrict__ Wq,
                                              const float* __restrict__ Wk,
                                              const float* __restrict__ Wv,
                                              const float* __restrict__ Wo,
                                              short* __restrict__ wt) {
  __shared__ float tile[32][33];
  const int mat = blockIdx.x >> 8;
  const int tix = blockIdx.x & 255;
  const int n0 = (tix & 15) * 32, k0 = (tix >> 4) * 32;
  const float* W = (mat == 0) ? Wq : (mat == 1) ? Wk : (mat == 2) ? Wv : Wo;
  const int tx = threadIdx.x & 31, ty = threadIdx.x >> 5;  // 32 x 8
#pragma unroll
  for (int i = 0; i < 4; ++i)
    tile[ty + 8 * i][tx] = W[(size_t)(k0 + ty + 8 * i) * 512 + n0 + tx];
  __syncthreads();
#pragma unroll
  for (int i = 0; i < 4; ++i) {
    int n = ty + 8 * i, k = tx;
    wt[((size_t)(mat * 512 + n0 + n) << 9) + k0 + k] = bf16b(tile[k][n]);
  }
}

#define WTLOAD(mat, ksv, nt) \
  (*(const short8v*)(wt + (((size_t)((mat)*512 + nw + (nt)*16 + lr)) << 9) + (ksv)*32 + lo * 8))
#define ALOAD(row, ksv) (*(const short8v*)(smem + (row)*1040 + (ksv)*64 + lo * 16))

// ---- fused MFMA kernel ----
__global__ __launch_bounds__(THREADS, 2) void fused_mfma(
    const float* __restrict__ query, const float* __restrict__ key_ant,
    const float* __restrict__ value_ant, const float* __restrict__ bias,
    const float* __restrict__ bq, const float* __restrict__ bk,
    const float* __restrict__ bv, const float* __restrict__ bo,
    const short* __restrict__ wt, float* __restrict__ out, float* __restrict__ top) {
  extern __shared__ char smem[];
  const int t = threadIdx.x, lane = t & 63, w = t >> 6;
  const int ble = blockIdx.x, e = ble & 7, bl = ble >> 3;
  const int lr = lane & 15, lo = lane >> 4;
  const int nw = w * 64;  // wave's N-slice base = head slice

  const float* QIN = query + (size_t)ble * 16 * 512;
  const float* KIN = key_ant + (size_t)ble * 32 * 512;
  const float* VIN = value_ant + (size_t)ble * 32 * 512;

  const int srow = t >> 7, scol4 = (t & 127) << 2;  // staging: thread's base row, col

  // ---- issue K then V stage loads (K first so K's waitcnt doesn't drain V) ----
  float4 kst[8], vst[8];
#pragma unroll
  for (int s = 0; s < 8; ++s) kst[s] = *(const float4*)&KIN[(srow + 4 * s) * 512 + scol4];
#pragma unroll
  for (int s = 0; s < 8; ++s) vst[s] = *(const float4*)&VIN[(srow + 4 * s) * 512 + scol4];
  // ---- write K tile to LDS (dep-waits on K loads only) ----
#pragma unroll
  for (int s = 0; s < 8; ++s) {
    short4v s4 = {bf16b(kst[s].x), bf16b(kst[s].y), bf16b(kst[s].z), bf16b(kst[s].w)};
    *(short4v*)(smem + (srow + 4 * s) * 1040 + scol4 * 2) = s4;
  }
  __syncthreads();

  // ================= K projection -> kp[32][520] @49920 =================
  {
    f32x4 acc[2][4] = {};
    short8v bA[4], bB[4];
#pragma unroll
    for (int nt = 0; nt < 4; ++nt) bA[nt] = WTLOAD(1, 0, nt);
#pragma unroll
    for (int nt = 0; nt < 4; ++nt) bB[nt] = WTLOAD(1, 1, nt);
#pragma unroll
    for (int ks = 0; ks < 16; ks += 2) {
      short8v a0 = ALOAD(lr, ks), a1 = ALOAD(lr + 16, ks);
#pragma unroll
      for (int nt = 0; nt < 4; ++nt) {
        acc[0][nt] = __builtin_amdgcn_mfma_f32_16x16x32_bf16(a0, bA[nt], acc[0][nt], 0, 0, 0);
        acc[1][nt] = __builtin_amdgcn_mfma_f32_16x16x32_bf16(a1, bA[nt], acc[1][nt], 0, 0, 0);
      }
      if (ks < 14) {
#pragma unroll
        for (int nt = 0; nt < 4; ++nt) bA[nt] = WTLOAD(1, ks + 2, nt);
      }
      short8v c0 = ALOAD(lr, ks + 1), c1 = ALOAD(lr + 16, ks + 1);
#pragma unroll
      for (int nt = 0; nt < 4; ++nt) {
        acc[0][nt] = __builtin_amdgcn_mfma_f32_16x16x32_bf16(c0, bB[nt], acc[0][nt], 0, 0, 0);
        acc[1][nt] = __builtin_amdgcn_mfma_f32_16x16x32_bf16(c1, bB[nt], acc[1][nt], 0, 0, 0);
      }
      if (ks < 14) {
#pragma unroll
        for (int nt = 0; nt < 4; ++nt) bB[nt] = WTLOAD(1, ks + 3, nt);
      }
    }
#pragma unroll
    for (int nt = 0; nt < 4; ++nt) {
      int n = nw + nt * 16 + lr;
      float bb = bk[n];
#pragma unroll
      for (int mt = 0; mt < 2; ++mt)
#pragma unroll
        for (int r = 0; r < 4; ++r)
          *(short*)(smem + 49920 + (mt * 16 + lo * 4 + r) * 1040 + n * 2) =
              bf16b(acc[mt][nt][r] + bb);
    }
  }
  __syncthreads();

  // ---- issue Q stage loads; write V tile to LDS ----
  float4 qst[4];
#pragma unroll
  for (int s = 0; s < 4; ++s) qst[s] = *(const float4*)&QIN[(srow + 4 * s) * 512 + scol4];
#pragma unroll
  for (int s = 0; s < 8; ++s) {
    short4v s4 = {bf16b(vst[s].x), bf16b(vst[s].y), bf16b(vst[s].z), bf16b(vst[s].w)};
    *(short4v*)(smem + (srow + 4 * s) * 1040 + scol4 * 2) = s4;
  }
  __syncthreads();

  // ================= V projection -> vpT[512][40] @83200 =================
  {
    f32x4 acc[2][4] = {};
    short8v bA[4], bB[4];
#pragma unroll
    for (int nt = 0; nt < 4; ++nt) bA[nt] = WTLOAD(2, 0, nt);
#pragma unroll
    for (int nt = 0; nt < 4; ++nt) bB[nt] = WTLOAD(2, 1, nt);
#pragma unroll
    for (int ks = 0; ks < 16; ks += 2) {
      short8v a0 = ALOAD(lr, ks), a1 = ALOAD(lr + 16, ks);
#pragma unroll
      for (int nt = 0; nt < 4; ++nt) {
        acc[0][nt] = __builtin_amdgcn_mfma_f32_16x16x32_bf16(a0, bA[nt], acc[0][nt], 0, 0, 0);
        acc[1][nt] = __builtin_amdgcn_mfma_f32_16x16x32_bf16(a1, bA[nt], acc[1][nt], 0, 0, 0);
      }
      if (ks < 14) {
#pragma unroll
        for (int nt = 0; nt < 4; ++nt) bA[nt] = WTLOAD(2, ks + 2, nt);
      }
      short8v c0 = ALOAD(lr, ks + 1), c1 = ALOAD(lr + 16, ks + 1);
#pragma unroll
      for (int nt = 0; nt < 4; ++nt) {
        acc[0][nt] = __builtin_amdgcn_mfma_f32_16x16x32_bf16(c0, bB[nt], acc[0][nt], 0, 0, 0);
        acc[1][nt] = __builtin_amdgcn_mfma_f32_16x16x32_bf16(c1, bB[nt], acc[1][nt], 0, 0, 0);
      }
      if (ks < 14) {
#pragma unroll
        for (int nt = 0; nt < 4; ++nt) bB[nt] = WTLOAD(2, ks + 3, nt);
      }
    }
#pragma unroll
    for (int nt = 0; nt < 4; ++nt) {
      int n = nw + nt * 16 + lr;
      float bb = bv[n];
#pragma unroll
      for (int mt = 0; mt < 2; ++mt) {
        short4v pk = {bf16b(acc[mt][nt][0] + bb), bf16b(acc[mt][nt][1] + bb),
                      bf16b(acc[mt][nt][2] + bb), bf16b(acc[mt][nt][3] + bb)};
        *(short4v*)(smem + 83200 + n * 80 + (mt * 16 + lo * 4) * 2) = pk;
      }
    }
  }
  __syncthreads();

  // ---- write Q tile to LDS (rows 0..15); issue bias prefetch ----
#pragma unroll
  for (int s = 0; s < 4; ++s) {
    short4v s4 = {bf16b(qst[s].x), bf16b(qst[s].y), bf16b(qst[s].z), bf16b(qst[s].w)};
    *(short4v*)(smem + (srow + 4 * s) * 1040 + scol4 * 2) = s4;
  }
  const float* brow = bias + (size_t)ble * 512;
  float bias8[8];
#pragma unroll
  for (int kt = 0; kt < 2; ++kt)
#pragma unroll
    for (int r = 0; r < 4; ++r)
      bias8[kt * 4 + r] = brow[(lo * 4 + r) * 32 + lr + 16 * kt];
  __syncthreads();

  // ================= Q projection -> qp[16][520] @33280 (x0.125) =================
  {
    f32x4 acc[4] = {};
    short8v bA[4], bB[4];
#pragma unroll
    for (int nt = 0; nt < 4; ++nt) bA[nt] = WTLOAD(0, 0, nt);
#pragma unroll
    for (int nt = 0; nt < 4; ++nt) bB[nt] = WTLOAD(0, 1, nt);
#pragma unroll
    for (int ks = 0; ks < 16; ks += 2) {
      short8v a0 = ALOAD(lr, ks);
#pragma unroll
      for (int nt = 0; nt < 4; ++nt)
        acc[nt] = __builtin_amdgcn_mfma_f32_16x16x32_bf16(a0, bA[nt], acc[nt], 0, 0, 0);
      if (ks < 14) {
#pragma unroll
        for (int nt = 0; nt < 4; ++nt) bA[nt] = WTLOAD(0, ks + 2, nt);
      }
      short8v c0 = ALOAD(lr, ks + 1);
#pragma unroll
      for (int nt = 0; nt < 4; ++nt)
        acc[nt] = __builtin_amdgcn_mfma_f32_16x16x32_bf16(c0, bB[nt], acc[nt], 0, 0, 0);
      if (ks < 14) {
#pragma unroll
        for (int nt = 0; nt < 4; ++nt) bB[nt] = WTLOAD(0, ks + 3, nt);
      }
    }
#pragma unroll
    for (int nt = 0; nt < 4; ++nt) {
      int n = nw + nt * 16 + lr;
      float bb = bq[n];
#pragma unroll
      for (int r = 0; r < 4; ++r)
        *(short*)(smem + 33280 + (lo * 4 + r) * 1040 + n * 2) = bf16b((acc[nt][r] + bb) * 0.125f);
    }
  }
  __syncthreads();  // also protects actS -> x reuse

  // ======== scores + softmax (wave-local) ========
  float attn8[8];
  {
    f32x4 sc[2] = {};
#pragma unroll
    for (int ks = 0; ks < 2; ++ks) {
      short8v aq = *(const short8v*)(smem + 33280 + lr * 1040 + (nw + ks * 32 + lo * 8) * 2);
#pragma unroll
      for (int kt = 0; kt < 2; ++kt) {
        short8v b =
            *(const short8v*)(smem + 49920 + (lr + 16 * kt) * 1040 + (nw + ks * 32 + lo * 8) * 2);
        sc[kt] = __builtin_amdgcn_mfma_f32_16x16x32_bf16(aq, b, sc[kt], 0, 0, 0);
      }
    }
    float s8[8];
#pragma unroll
    for (int kt = 0; kt < 2; ++kt)
#pragma unroll
      for (int r = 0; r < 4; ++r) s8[kt * 4 + r] = sc[kt][r] + bias8[kt * 4 + r];
#pragma unroll
    for (int r = 0; r < 4; ++r) {
      float mx = fmaxf(s8[r], s8[4 + r]);
#pragma unroll
      for (int off = 1; off < 16; off <<= 1) mx = fmaxf(mx, __shfl_xor(mx, off, 16));
      float p0 = expf(s8[r] - mx), p1 = expf(s8[4 + r] - mx);
      float sm = p0 + p1;
#pragma unroll
      for (int off = 1; off < 16; off <<= 1) sm += __shfl_xor(sm, off, 16);
      float inv = 1.f / sm;
      attn8[r] = p0 * inv;
      attn8[4 + r] = p1 * inv;
    }
#pragma unroll
    for (int kt = 0; kt < 2; ++kt)
#pragma unroll
      for (int r = 0; r < 4; ++r) {
        int q = lo * 4 + r, key = lr + 16 * kt;
        *(short*)(smem + 124160 + w * 1280 + q * 80 + key * 2) = bf16b(attn8[kt * 4 + r]);
        if (((w & 3) == 0) && lo < 2)
          top[(((size_t)bl * 16 + 2 * e + (w >> 2)) * 32 + 4 * q + (key >> 3)) * 8 + (key & 7)] =
              attn8[kt * 4 + r];
      }
  }

  // ================= PV -> x[16][520] bf16 @0 =================
  {
    f32x4 xacc[4] = {};
    short8v ap = *(const short8v*)(smem + 124160 + w * 1280 + lr * 80 + lo * 16);
#pragma unroll
    for (int nt = 0; nt < 4; ++nt) {
      short8v b = *(const short8v*)(smem + 83200 + (nw + nt * 16 + lr) * 80 + lo * 16);
      xacc[nt] = __builtin_amdgcn_mfma_f32_16x16x32_bf16(ap, b, xacc[nt], 0, 0, 0);
    }
#pragma unroll
    for (int nt = 0; nt < 4; ++nt)
#pragma unroll
      for (int r = 0; r < 4; ++r)
        *(short*)(smem + (lo * 4 + r) * 1040 + (nw + nt * 16 + lr) * 2) = bf16b(xacc[nt][r]);
  }
  // prefetch out-proj first wt fragments across the barrier
  short8v oA[4], oB[4];
#pragma unroll
  for (int nt = 0; nt < 4; ++nt) oA[nt] = WTLOAD(3, 0, nt);
#pragma unroll
  for (int nt = 0; nt < 4; ++nt) oB[nt] = WTLOAD(3, 1, nt);
  __syncthreads();

  // ================= out proj: out = x @ Wo + bo (f32 global) =================
  {
    f32x4 acc[4] = {};
#pragma unroll
    for (int ks = 0; ks < 16; ks += 2) {
      short8v a0 = ALOAD(lr, ks);
#pragma unroll
      for (int nt = 0; nt < 4; ++nt)
        acc[nt] = __builtin_amdgcn_mfma_f32_16x16x32_bf16(a0, oA[nt], acc[nt], 0, 0, 0);
      if (ks < 14) {
#pragma unroll
        for (int nt = 0; nt < 4; ++nt) oA[nt] = WTLOAD(3, ks + 2, nt);
      }
      short8v c0 = ALOAD(lr, ks + 1);
#pragma unroll
      for (int nt = 0; nt < 4; ++nt)
        acc[nt] = __builtin_amdgcn_mfma_f32_16x16x32_bf16(c0, oB[nt], acc[nt], 0, 0, 0);
      if (ks < 14) {
#pragma unroll
        for (int nt = 0; nt < 4; ++nt) oB[nt] = WTLOAD(3, ks + 3, nt);
      }
    }
#pragma unroll
    for (int nt = 0; nt < 4; ++nt) {
      int n = nw + nt * 16 + lr;
      float bb = bo[n];
#pragma unroll
      for (int r = 0; r < 4; ++r)
        out[((size_t)ble * 16 + lo * 4 + r) * 512 + n] = acc[nt][r] + bb;
    }
  }
}

// ================= fallback: proven R12 f32 kernel =================
__global__ __launch_bounds__(THREADS) void fused_attn(
    const float* __restrict__ query, const float* __restrict__ key_ant,
    const float* __restrict__ value_ant, const float* __restrict__ bias,
    const float* __restrict__ Wq, const float* __restrict__ bq,
    const float* __restrict__ Wk, const float* __restrict__ bk,
    const float* __restrict__ Wv, const float* __restrict__ bv,
    const float* __restrict__ Wo, const float* __restrict__ bo,
    float* __restrict__ out, float* __restrict__ top) {
  extern __shared__ char smem[];
  float* qinh = (float*)(smem);
  float* kinh = (float*)(smem + 16384);
  float* s = (float*)(smem);
  float* qp = (float*)(smem + 49152);
  float* kp = (float*)(smem + 81920);
  float* vp = (float*)(smem + 49152);
  float* x = (float*)(smem + 114688);
  const int t = threadIdx.x;
  const int ble = blockIdx.x;
  const int e = ble & 7, bl = ble >> 3;
  const float* QIN = query + (size_t)ble * 16 * 512;
  const float* KIN = key_ant + (size_t)ble * 32 * 512;
  const float* VIN = value_ant + (size_t)ble * 32 * 512;
  {
    float acc[16];
#pragma unroll
    for (int w = 0; w < 16; ++w) acc[w] = 0.f;
    for (int half = 0; half < 2; ++half) {
      for (int i = t; i < 4096; i += THREADS) {
        int w = i >> 8, h = i & 255;
        qinh[i] = QIN[w * 512 + half * 256 + h];
      }
      __syncthreads();
      for (int h0 = 0; h0 < 256; h0 += 8) {
        float wr[8];
#pragma unroll
        for (int r = 0; r < 8; ++r) wr[r] = Wq[(size_t)(half * 256 + h0 + r) * 512 + t];
#pragma unroll
        for (int r = 0; r < 8; ++r)
#pragma unroll
          for (int w = 0; w < 16; ++w) acc[w] = fmaf(qinh[w * 256 + h0 + r], wr[r], acc[w]);
      }
      __syncthreads();
    }
    float bqv = bq[t];
#pragma unroll
    for (int w = 0; w < 16; ++w) qp[w * 512 + t] = (acc[w] + bqv) * 0.125f;
  }
  {
    float acc[32];
#pragma unroll
    for (int w = 0; w < 32; ++w) acc[w] = 0.f;
    for (int half = 0; half < 2; ++half) {
      for (int i = t; i < 8192; i += THREADS) {
        int w = i >> 8, h = i & 255;
        kinh[i] = KIN[w * 512 + half * 256 + h];
      }
      __syncthreads();
      for (int h0 = 0; h0 < 256; h0 += 8) {
        float wr[8];
#pragma unroll
        for (int r = 0; r < 8; ++r) wr[r] = Wk[(size_t)(half * 256 + h0 + r) * 512 + t];
#pragma unroll
        for (int r = 0; r < 8; ++r)
#pragma unroll
          for (int w = 0; w < 32; ++w) acc[w] = fmaf(kinh[w * 256 + h0 + r], wr[r], acc[w]);
      }
      __syncthreads();
    }
    float bkv = bk[t];
#pragma unroll
    for (int w = 0; w < 32; ++w) kp[w * 512 + (t ^ ((w & 7) << 2))] = acc[w] + bkv;
  }
  __syncthreads();
  for (int i = 0; i < 8; ++i) {
    int idx = t + i * THREADS;
    int n = idx >> 9, rem = idx & 511, q = rem >> 5, k = rem & 31;
    const float* qrow = qp + q * 512 + n * 64;
    const float* krow = kp + k * 512 + n * 64;
    int xo = (k & 7) << 2;
    float a = 0.f;
#pragma unroll
    for (int d = 0; d < 64; ++d) a = fmaf(qrow[d], krow[d ^ xo], a);
    s[idx] = a + bias[(size_t)ble * 512 + q * 32 + k];
  }
  __syncthreads();
  if (t < 128) {
    int n = t >> 4, q = t & 15;
    float* row = s + n * 512 + q * 32;
    float mx = row[0];
#pragma unroll
    for (int k = 1; k < 32; ++k) mx = fmaxf(mx, row[k]);
    float sum = 0.f;
#pragma unroll
    for (int k = 0; k < 32; ++k) {
      float p = expf(row[k] - mx);
      row[k] = p;
      sum += p;
    }
    float inv = 1.f / sum;
#pragma unroll
    for (int k = 0; k < 32; ++k) row[k] *= inv;
    if (((n & 3) == 0) && q < 8) {
      int qp_ = 2 * e + (n >> 2);
#pragma unroll
      for (int k = 0; k < 32; ++k) {
        int kp_ = 4 * q + (k >> 3), ep_ = k & 7;
        top[(((size_t)bl * 16 + qp_) * 32 + kp_) * 8 + ep_] = row[k];
      }
    }
  }
  __syncthreads();
  {
    float acc[32];
#pragma unroll
    for (int w = 0; w < 32; ++w) acc[w] = 0.f;
    for (int half = 0; half < 2; ++half) {
      for (int i = t; i < 8192; i += THREADS) {
        int w = i >> 8, h = i & 255;
        kinh[i] = VIN[w * 512 + half * 256 + h];
      }
      __syncthreads();
      for (int h0 = 0; h0 < 256; h0 += 8) {
        float wr[8];
#pragma unroll
        for (int r = 0; r < 8; ++r) wr[r] = Wv[(size_t)(half * 256 + h0 + r) * 512 + t];
#pragma unroll
        for (int r = 0; r < 8; ++r)
#pragma unroll
          for (int w = 0; w < 32; ++w) acc[w] = fmaf(kinh[w * 256 + h0 + r], wr[r], acc[w]);
      }
      __syncthreads();
    }
    float bvv = bv[t];
#pragma unroll
    for (int w = 0; w < 32; ++w) vp[w * 512 + (t ^ ((w & 7) << 2))] = acc[w] + bvv;
  }
  __syncthreads();
  {
    int j = t, n = j >> 6;
    float xa[16];
#pragma unroll
    for (int q = 0; q < 16; ++q) xa[q] = 0.f;
#pragma unroll
    for (int k = 0; k < 32; ++k) {
      float pv = vp[k * 512 + (j ^ ((k & 7) << 2))];
      const float* prow = s + n * 512 + k;
#pragma unroll
      for (int q = 0; q < 16; ++q) xa[q] = fmaf(prow[q * 32], pv, xa[q]);
    }
#pragma unroll
    for (int q = 0; q < 16; ++q) x[q * 512 + j] = xa[q];
  }
  __syncthreads();
  {
    float acc[16];
#pragma unroll
    for (int w = 0; w < 16; ++w) acc[w] = 0.f;
    for (int h0 = 0; h0 < 512; h0 += 8) {
      float wr[8];
#pragma unroll
      for (int r = 0; r < 8; ++r) wr[r] = Wo[(size_t)(h0 + r) * 512 + t];
#pragma unroll
      for (int r = 0; r < 8; ++r)
#pragma unroll
        for (int w = 0; w < 16; ++w) acc[w] = fmaf(x[w * 512 + h0 + r], wr[r], acc[w]);
    }
    float bov = bo[t];
#pragma unroll
    for (int w = 0; w < 16; ++w) out[((size_t)ble * 16 + w) * 512 + t] = acc[w] + bov;
  }
}

extern "C" void kernel_launch(void* const* d_in, const int* in_sizes, int n_in,
                              void* d_out, int out_size, void* d_ws, size_t ws_size,
                              hipStream_t stream) {
  const float* query = (const float*)d_in[0];
  const float* key_a = (const float*)d_in[1];
  const float* val_a = (const float*)d_in[2];
  const float* bias = (const float*)d_in[3];
  const float* Wq = (const float*)d_in[4];
  const float* bq = (const float*)d_in[5];
  const float* Wk = (const float*)d_in[6];
  const float* bk = (const float*)d_in[7];
  const float* Wv = (const float*)d_in[8];
  const float* bv = (const float*)d_in[9];
  const float* Wo = (const float*)d_in[10];
  const float* bo = (const float*)d_in[11];
  float* out = (float*)d_out;
  float* top = out + 16777216;

  if (ws_size >= (size_t)(4 * 512 * 512 * sizeof(short))) {
    short* wt = (short*)d_ws;
    prep_w<<<1024, 256, 0, stream>>>(Wq, Wk, Wv, Wo, wt);
    fused_mfma<<<2048, THREADS, 134400, stream>>>(query, key_a, val_a, bias, bq, bk, bv, bo,
                                                  wt, out, top);
  } else {
    fused_attn<<<2048, THREADS, 147456, stream>>>(query, key_a, val_a, bias, Wq, bq, Wk, bk,
                                                  Wv, bv, Wo, bo, out, top);
  }
}

// Round 15
// 418.815 us; speedup vs baseline: 11.7986x; 1.2992x over previous
//
#include <hip/hip_runtime.h>
#include <hip/hip_bf16.h>

// Shapes (fixed): B=4, L=64, E=8, Q=16, K=32, H=512, NH=8, HD=64
// R15: TLP pivot. R14 diagnosis: compiler refuses high-VGPR ILP schedule (84 regs,
// serial wt-load chains, all pipes <8% busy, 1 block/CU from 134KB LDS).
// New path (needs ws >= 162MB): prep_w -> 3x proj_gemm (64-row tiles, 10KB LDS,
// 2 blocks/CU) writing qp/kp/vpT bf16 to ws -> attn_tail (26.9KB LDS, 2 blocks/CU).
// Fragment loads all contiguous 16B. Lane mappings verbatim from R14 (passed).
// Fallback (2MB <= ws < 162MB): R14 fused kernel (passed, 544us).

#define THREADS 512

typedef __attribute__((ext_vector_type(8))) short short8v;
typedef __attribute__((ext_vector_type(4))) short short4v;
typedef __attribute__((ext_vector_type(4))) float f32x4;

__device__ __forceinline__ short bf16b(float f) {
  __hip_bfloat16 h = __float2bfloat16(f);
  return *reinterpret_cast<short*>(&h);
}

// ---- W prep: wt[mat][n][k] = bf16(W[k][n]) ----
__global__ __launch_bounds__(256) void prep_w(const float* __restrict__ Wq,
                                              const float* __restrict__ Wk,
                                              const float* __restrict__ Wv,
                                              const float* __restrict__ Wo,
                                              short* __restrict__ wt) {
  __shared__ float tile[32][33];
  const int mat = blockIdx.x >> 8;
  const int tix = blockIdx.x & 255;
  const int n0 = (tix & 15) * 32, k0 = (tix >> 4) * 32;
  const float* W = (mat == 0) ? Wq : (mat == 1) ? Wk : (mat == 2) ? Wv : Wo;
  const int tx = threadIdx.x & 31, ty = threadIdx.x >> 5;
#pragma unroll
  for (int i = 0; i < 4; ++i)
    tile[ty + 8 * i][tx] = W[(size_t)(k0 + ty + 8 * i) * 512 + n0 + tx];
  __syncthreads();
#pragma unroll
  for (int i = 0; i < 4; ++i) {
    int n = ty + 8 * i, k = tx;
    wt[((size_t)(mat * 512 + n0 + n) << 9) + k0 + k] = bf16b(tile[k][n]);
  }
}

// ---- projection GEMM: 64 rows x 512 cols per block; MAT 0=Q(row-major,x0.125),
// 1=K(row-major), 2=V(transposed vpT[ble][n][key]) ----
template <int MAT>
__global__ __launch_bounds__(THREADS, 4) void proj_gemm(const float* __restrict__ A,
                                                        const float* __restrict__ bvec,
                                                        const short* __restrict__ wt,
                                                        short* __restrict__ C) {
  __shared__ short As[2][64][40];  // 40-short stride: 2-way max bank alias on b128 reads
  const int t = threadIdx.x, lane = t & 63, w = t >> 6;
  const int lr = lane & 15, lo = lane >> 4;
  const int nw = w * 64;
  const int R0 = blockIdx.x * 64;
  const int srow = t >> 3, scol4 = (t & 7) << 2;

  float4 ld = *(const float4*)&A[(size_t)(R0 + srow) * 512 + scol4];
  {
    short4v s4 = {bf16b(ld.x), bf16b(ld.y), bf16b(ld.z), bf16b(ld.w)};
    *(short4v*)&As[0][srow][scol4] = s4;
  }
  __syncthreads();

  f32x4 acc[4][4] = {};
#pragma unroll
  for (int c = 0; c < 16; ++c) {
    float4 ldn;
    if (c < 15) ldn = *(const float4*)&A[(size_t)(R0 + srow) * 512 + (c + 1) * 32 + scol4];
    short8v bfr[4];
#pragma unroll
    for (int nt = 0; nt < 4; ++nt)
      bfr[nt] = *(const short8v*)(wt + (((size_t)(MAT * 512 + nw + nt * 16 + lr)) << 9) +
                                  c * 32 + lo * 8);
#pragma unroll
    for (int mt = 0; mt < 4; ++mt) {
      short8v a = *(const short8v*)&As[c & 1][mt * 16 + lr][lo * 8];
#pragma unroll
      for (int nt = 0; nt < 4; ++nt)
        acc[mt][nt] = __builtin_amdgcn_mfma_f32_16x16x32_bf16(a, bfr[nt], acc[mt][nt], 0, 0, 0);
    }
    if (c < 15) {
      short4v s4 = {bf16b(ldn.x), bf16b(ldn.y), bf16b(ldn.z), bf16b(ldn.w)};
      *(short4v*)&As[(c + 1) & 1][srow][scol4] = s4;
    }
    __syncthreads();
  }

#pragma unroll
  for (int nt = 0; nt < 4; ++nt) {
    int n = nw + nt * 16 + lr;
    float bb = bvec[n];
#pragma unroll
    for (int mt = 0; mt < 4; ++mt) {
      if (MAT == 2) {
        int rl0 = mt * 16 + lo * 4;  // key0..key0+3 stay in one ble (aligned by 4)
        int ble2 = (R0 + rl0) >> 5, key0 = rl0 & 31;
        short4v s4 = {bf16b(acc[mt][nt][0] + bb), bf16b(acc[mt][nt][1] + bb),
                      bf16b(acc[mt][nt][2] + bb), bf16b(acc[mt][nt][3] + bb)};
        *(short4v*)(C + (size_t)ble2 * 16384 + n * 32 + key0) = s4;
      } else {
#pragma unroll
        for (int r = 0; r < 4; ++r) {
          int rl = mt * 16 + lo * 4 + r;
          float v = acc[mt][nt][r] + bb;
          if (MAT == 0) {
            int ble2 = (R0 + rl) >> 4, q = rl & 15;
            C[(size_t)ble2 * 8192 + q * 512 + n] = bf16b(v * 0.125f);
          } else {
            int ble2 = (R0 + rl) >> 5, key = rl & 31;
            C[(size_t)ble2 * 16384 + key * 512 + n] = bf16b(v);
          }
        }
      }
    }
  }
}

// ---- attention tail: scores + softmax + top + PV + out-proj; one block per ble ----
__global__ __launch_bounds__(THREADS, 4) void attn_tail(
    const short* __restrict__ qp, const short* __restrict__ kp, const short* __restrict__ vpT,
    const float* __restrict__ bias, const float* __restrict__ bo, const short* __restrict__ wt,
    float* __restrict__ out, float* __restrict__ top) {
  extern __shared__ char smem[];  // p[8][16][40]s @0 (10240B) ; x[16][520]s @10240 (16640B)
  const int t = threadIdx.x, lane = t & 63, w = t >> 6;
  const int ble = blockIdx.x, e = ble & 7, bl = ble >> 3;
  const int lr = lane & 15, lo = lane >> 4;
  const int nw = w * 64;

  const short* qb = qp + (size_t)ble * 8192;
  const short* kb = kp + (size_t)ble * 16384;
  const short* vb = vpT + (size_t)ble * 16384;

  const float* brow = bias + (size_t)ble * 512;
  float bias8[8];
#pragma unroll
  for (int kt = 0; kt < 2; ++kt)
#pragma unroll
    for (int r = 0; r < 4; ++r)
      bias8[kt * 4 + r] = brow[(lo * 4 + r) * 32 + lr + 16 * kt];

  // scores (wave = head w; d-slice [64w,64w+64))
  f32x4 sc[2] = {};
#pragma unroll
  for (int ks = 0; ks < 2; ++ks) {
    short8v aq = *(const short8v*)(qb + lr * 512 + nw + ks * 32 + lo * 8);
#pragma unroll
    for (int kt = 0; kt < 2; ++kt) {
      short8v b = *(const short8v*)(kb + (lr + 16 * kt) * 512 + nw + ks * 32 + lo * 8);
      sc[kt] = __builtin_amdgcn_mfma_f32_16x16x32_bf16(aq, b, sc[kt], 0, 0, 0);
    }
  }
  // softmax rows (C layout: row=q=lo*4+r, col=key=lr+16kt); reduce over lr via shfl16
  float attn8[8];
  {
    float s8[8];
#pragma unroll
    for (int kt = 0; kt < 2; ++kt)
#pragma unroll
      for (int r = 0; r < 4; ++r) s8[kt * 4 + r] = sc[kt][r] + bias8[kt * 4 + r];
#pragma unroll
    for (int r = 0; r < 4; ++r) {
      float mx = fmaxf(s8[r], s8[4 + r]);
#pragma unroll
      for (int off = 1; off < 16; off <<= 1) mx = fmaxf(mx, __shfl_xor(mx, off, 16));
      float p0 = expf(s8[r] - mx), p1 = expf(s8[4 + r] - mx);
      float sm = p0 + p1;
#pragma unroll
      for (int off = 1; off < 16; off <<= 1) sm += __shfl_xor(sm, off, 16);
      float inv = 1.f / sm;
      attn8[r] = p0 * inv;
      attn8[4 + r] = p1 * inv;
    }
#pragma unroll
    for (int kt = 0; kt < 2; ++kt)
#pragma unroll
      for (int r = 0; r < 4; ++r) {
        int q = lo * 4 + r, key = lr + 16 * kt;
        *(short*)(smem + w * 1280 + q * 80 + key * 2) = bf16b(attn8[kt * 4 + r]);
        if (((w & 3) == 0) && lo < 2)
          top[(((size_t)bl * 16 + 2 * e + (w >> 2)) * 32 + 4 * q + (key >> 3)) * 8 + (key & 7)] =
              attn8[kt * 4 + r];
      }
  }

  // PV: wave-local p (in-order LDS per wave; no barrier needed, as R14)
  {
    f32x4 xacc[4] = {};
    short8v ap = *(const short8v*)(smem + w * 1280 + lr * 80 + lo * 16);
#pragma unroll
    for (int nt = 0; nt < 4; ++nt) {
      short8v b = *(const short8v*)(vb + (nw + nt * 16 + lr) * 32 + lo * 8);
      xacc[nt] = __builtin_amdgcn_mfma_f32_16x16x32_bf16(ap, b, xacc[nt], 0, 0, 0);
    }
#pragma unroll
    for (int nt = 0; nt < 4; ++nt)
#pragma unroll
      for (int r = 0; r < 4; ++r)
        *(short*)(smem + 10240 + (lo * 4 + r) * 1040 + (nw + nt * 16 + lr) * 2) =
            bf16b(xacc[nt][r]);
  }
  __syncthreads();  // x is cross-wave for out-proj

  // out proj: out = x @ Wo + bo
  {
    f32x4 oacc[4] = {};
#pragma unroll
    for (int ks = 0; ks < 16; ++ks) {
      short8v a = *(const short8v*)(smem + 10240 + lr * 1040 + ks * 64 + lo * 16);
#pragma unroll
      for (int nt = 0; nt < 4; ++nt) {
        short8v b = *(const short8v*)(wt + (((size_t)(1536 + nw + nt * 16 + lr)) << 9) +
                                      ks * 32 + lo * 8);
        oacc[nt] = __builtin_amdgcn_mfma_f32_16x16x32_bf16(a, b, oacc[nt], 0, 0, 0);
      }
    }
#pragma unroll
    for (int nt = 0; nt < 4; ++nt) {
      int n = nw + nt * 16 + lr;
      float bb = bo[n];
#pragma unroll
      for (int r = 0; r < 4; ++r)
        out[((size_t)ble * 16 + lo * 4 + r) * 512 + n] = oacc[nt][r] + bb;
    }
  }
}

// ================= fallback: R14 fused kernel (passed, 544us) =================
#define WTLOAD(mat, ksv, nt) \
  (*(const short8v*)(wt + (((size_t)((mat)*512 + nw + (nt)*16 + lr)) << 9) + (ksv)*32 + lo * 8))
#define ALOAD(row, ksv) (*(const short8v*)(smem + (row)*1040 + (ksv)*64 + lo * 16))

__global__ __launch_bounds__(THREADS, 2) void fused_mfma(
    const float* __restrict__ query, const float* __restrict__ key_ant,
    const float* __restrict__ value_ant, const float* __restrict__ bias,
    const float* __restrict__ bq, const float* __restrict__ bk,
    const float* __restrict__ bv, const float* __restrict__ bo,
    const short* __restrict__ wt, float* __restrict__ out, float* __restrict__ top) {
  extern __shared__ char smem[];
  const int t = threadIdx.x, lane = t & 63, w = t >> 6;
  const int ble = blockIdx.x, e = ble & 7, bl = ble >> 3;
  const int lr = lane & 15, lo = lane >> 4;
  const int nw = w * 64;
  const float* QIN = query + (size_t)ble * 16 * 512;
  const float* KIN = key_ant + (size_t)ble * 32 * 512;
  const float* VIN = value_ant + (size_t)ble * 32 * 512;
  const int srow = t >> 7, scol4 = (t & 127) << 2;

  float4 kst[8], vst[8];
#pragma unroll
  for (int s = 0; s < 8; ++s) kst[s] = *(const float4*)&KIN[(srow + 4 * s) * 512 + scol4];
#pragma unroll
  for (int s = 0; s < 8; ++s) vst[s] = *(const float4*)&VIN[(srow + 4 * s) * 512 + scol4];
#pragma unroll
  for (int s = 0; s < 8; ++s) {
    short4v s4 = {bf16b(kst[s].x), bf16b(kst[s].y), bf16b(kst[s].z), bf16b(kst[s].w)};
    *(short4v*)(smem + (srow + 4 * s) * 1040 + scol4 * 2) = s4;
  }
  __syncthreads();
  {
    f32x4 acc[2][4] = {};
    for (int ks = 0; ks < 16; ++ks) {
      short8v a0 = ALOAD(lr, ks), a1 = ALOAD(lr + 16, ks);
#pragma unroll
      for (int nt = 0; nt < 4; ++nt) {
        short8v b = WTLOAD(1, ks, nt);
        acc[0][nt] = __builtin_amdgcn_mfma_f32_16x16x32_bf16(a0, b, acc[0][nt], 0, 0, 0);
        acc[1][nt] = __builtin_amdgcn_mfma_f32_16x16x32_bf16(a1, b, acc[1][nt], 0, 0, 0);
      }
    }
#pragma unroll
    for (int nt = 0; nt < 4; ++nt) {
      int n = nw + nt * 16 + lr;
      float bb = bk[n];
#pragma unroll
      for (int mt = 0; mt < 2; ++mt)
#pragma unroll
        for (int r = 0; r < 4; ++r)
          *(short*)(smem + 49920 + (mt * 16 + lo * 4 + r) * 1040 + n * 2) =
              bf16b(acc[mt][nt][r] + bb);
    }
  }
  __syncthreads();
  float4 qst[4];
#pragma unroll
  for (int s = 0; s < 4; ++s) qst[s] = *(const float4*)&QIN[(srow + 4 * s) * 512 + scol4];
#pragma unroll
  for (int s = 0; s < 8; ++s) {
    short4v s4 = {bf16b(vst[s].x), bf16b(vst[s].y), bf16b(vst[s].z), bf16b(vst[s].w)};
    *(short4v*)(smem + (srow + 4 * s) * 1040 + scol4 * 2) = s4;
  }
  __syncthreads();
  {
    f32x4 acc[2][4] = {};
    for (int ks = 0; ks < 16; ++ks) {
      short8v a0 = ALOAD(lr, ks), a1 = ALOAD(lr + 16, ks);
#pragma unroll
      for (int nt = 0; nt < 4; ++nt) {
        short8v b = WTLOAD(2, ks, nt);
        acc[0][nt] = __builtin_amdgcn_mfma_f32_16x16x32_bf16(a0, b, acc[0][nt], 0, 0, 0);
        acc[1][nt] = __builtin_amdgcn_mfma_f32_16x16x32_bf16(a1, b, acc[1][nt], 0, 0, 0);
      }
    }
#pragma unroll
    for (int nt = 0; nt < 4; ++nt) {
      int n = nw + nt * 16 + lr;
      float bb = bv[n];
#pragma unroll
      for (int mt = 0; mt < 2; ++mt) {
        short4v pk = {bf16b(acc[mt][nt][0] + bb), bf16b(acc[mt][nt][1] + bb),
                      bf16b(acc[mt][nt][2] + bb), bf16b(acc[mt][nt][3] + bb)};
        *(short4v*)(smem + 83200 + n * 80 + (mt * 16 + lo * 4) * 2) = pk;
      }
    }
  }
  __syncthreads();
#pragma unroll
  for (int s = 0; s < 4; ++s) {
    short4v s4 = {bf16b(qst[s].x), bf16b(qst[s].y), bf16b(qst[s].z), bf16b(qst[s].w)};
    *(short4v*)(smem + (srow + 4 * s) * 1040 + scol4 * 2) = s4;
  }
  const float* brow = bias + (size_t)ble * 512;
  float bias8[8];
#pragma unroll
  for (int kt = 0; kt < 2; ++kt)
#pragma unroll
    for (int r = 0; r < 4; ++r) bias8[kt * 4 + r] = brow[(lo * 4 + r) * 32 + lr + 16 * kt];
  __syncthreads();
  {
    f32x4 acc[4] = {};
    for (int ks = 0; ks < 16; ++ks) {
      short8v a0 = ALOAD(lr, ks);
#pragma unroll
      for (int nt = 0; nt < 4; ++nt)
        acc[nt] = __builtin_amdgcn_mfma_f32_16x16x32_bf16(a0, WTLOAD(0, ks, nt), acc[nt], 0, 0, 0);
    }
#pragma unroll
    for (int nt = 0; nt < 4; ++nt) {
      int n = nw + nt * 16 + lr;
      float bb = bq[n];
#pragma unroll
      for (int r = 0; r < 4; ++r)
        *(short*)(smem + 33280 + (lo * 4 + r) * 1040 + n * 2) = bf16b((acc[nt][r] + bb) * 0.125f);
    }
  }
  __syncthreads();
  float attn8[8];
  {
    f32x4 sc[2] = {};
#pragma unroll
    for (int ks = 0; ks < 2; ++ks) {
      short8v aq = *(const short8v*)(smem + 33280 + lr * 1040 + (nw + ks * 32 + lo * 8) * 2);
#pragma unroll
      for (int kt = 0; kt < 2; ++kt) {
        short8v b =
            *(const short8v*)(smem + 49920 + (lr + 16 * kt) * 1040 + (nw + ks * 32 + lo * 8) * 2);
        sc[kt] = __builtin_amdgcn_mfma_f32_16x16x32_bf16(aq, b, sc[kt], 0, 0, 0);
      }
    }
    float s8[8];
#pragma unroll
    for (int kt = 0; kt < 2; ++kt)
#pragma unroll
      for (int r = 0; r < 4; ++r) s8[kt * 4 + r] = sc[kt][r] + bias8[kt * 4 + r];
#pragma unroll
    for (int r = 0; r < 4; ++r) {
      float mx = fmaxf(s8[r], s8[4 + r]);
#pragma unroll
      for (int off = 1; off < 16; off <<= 1) mx = fmaxf(mx, __shfl_xor(mx, off, 16));
      float p0 = expf(s8[r] - mx), p1 = expf(s8[4 + r] - mx);
      float sm = p0 + p1;
#pragma unroll
      for (int off = 1; off < 16; off <<= 1) sm += __shfl_xor(sm, off, 16);
      float inv = 1.f / sm;
      attn8[r] = p0 * inv;
      attn8[4 + r] = p1 * inv;
    }
#pragma unroll
    for (int kt = 0; kt < 2; ++kt)
#pragma unroll
      for (int r = 0; r < 4; ++r) {
        int q = lo * 4 + r, key = lr + 16 * kt;
        *(short*)(smem + 124160 + w * 1280 + q * 80 + key * 2) = bf16b(attn8[kt * 4 + r]);
        if (((w & 3) == 0) && lo < 2)
          top[(((size_t)bl * 16 + 2 * e + (w >> 2)) * 32 + 4 * q + (key >> 3)) * 8 + (key & 7)] =
              attn8[kt * 4 + r];
      }
  }
  {
    f32x4 xacc[4] = {};
    short8v ap = *(const short8v*)(smem + 124160 + w * 1280 + lr * 80 + lo * 16);
#pragma unroll
    for (int nt = 0; nt < 4; ++nt) {
      short8v b = *(const short8v*)(smem + 83200 + (nw + nt * 16 + lr) * 80 + lo * 16);
      xacc[nt] = __builtin_amdgcn_mfma_f32_16x16x32_bf16(ap, b, xacc[nt], 0, 0, 0);
    }
#pragma unroll
    for (int nt = 0; nt < 4; ++nt)
#pragma unroll
      for (int r = 0; r < 4; ++r)
        *(short*)(smem + (lo * 4 + r) * 1040 + (nw + nt * 16 + lr) * 2) = bf16b(xacc[nt][r]);
  }
  __syncthreads();
  {
    f32x4 acc[4] = {};
    for (int ks = 0; ks < 16; ++ks) {
      short8v a0 = ALOAD(lr, ks);
#pragma unroll
      for (int nt = 0; nt < 4; ++nt)
        acc[nt] = __builtin_amdgcn_mfma_f32_16x16x32_bf16(a0, WTLOAD(3, ks, nt), acc[nt], 0, 0, 0);
    }
#pragma unroll
    for (int nt = 0; nt < 4; ++nt) {
      int n = nw + nt * 16 + lr;
      float bb = bo[n];
#pragma unroll
      for (int r = 0; r < 4; ++r)
        out[((size_t)ble * 16 + lo * 4 + r) * 512 + n] = acc[nt][r] + bb;
    }
  }
}

extern "C" void kernel_launch(void* const* d_in, const int* in_sizes, int n_in,
                              void* d_out, int out_size, void* d_ws, size_t ws_size,
                              hipStream_t stream) {
  const float* query = (const float*)d_in[0];
  const float* key_a = (const float*)d_in[1];
  const float* val_a = (const float*)d_in[2];
  const float* bias = (const float*)d_in[3];
  const float* Wq = (const float*)d_in[4];
  const float* bq = (const float*)d_in[5];
  const float* Wk = (const float*)d_in[6];
  const float* bk = (const float*)d_in[7];
  const float* Wv = (const float*)d_in[8];
  const float* bv = (const float*)d_in[9];
  const float* Wo = (const float*)d_in[10];
  const float* bo = (const float*)d_in[11];
  float* out = (float*)d_out;
  float* top = out + 16777216;

  const size_t NEED = 169869312ULL;  // wt 2MB + qp 32MB + kp 64MB + vpT 64MB
  if (ws_size >= NEED) {
    short* wt = (short*)d_ws;
    short* qpw = (short*)((char*)d_ws + 2097152);
    short* kpw = (short*)((char*)d_ws + 35651584);
    short* vpw = (short*)((char*)d_ws + 102760448);
    prep_w<<<1024, 256, 0, stream>>>(Wq, Wk, Wv, Wo, wt);
    proj_gemm<0><<<512, THREADS, 0, stream>>>(query, bq, wt, qpw);
    proj_gemm<1><<<1024, THREADS, 0, stream>>>(key_a, bk, wt, kpw);
    proj_gemm<2><<<1024, THREADS, 0, stream>>>(val_a, bv, wt, vpw);
    attn_tail<<<2048, THREADS, 26880, stream>>>(qpw, kpw, vpw, bias, bo, wt, out, top);
  } else {
    short* wt = (short*)d_ws;  // ws >= 2MB proven (R13/R14 ran this path)
    prep_w<<<1024, 256, 0, stream>>>(Wq, Wk, Wv, Wo, wt);
    fused_mfma<<<2048, THREADS, 134400, stream>>>(query, key_a, val_a, bias, bq, bk, bv, bo,
                                                  wt, out, top);
  }
}

// Round 16
// 331.142 us; speedup vs baseline: 14.9224x; 1.2648x over previous
//
#include <hip/hip_runtime.h>
#include <hip/hip_bf16.h>

// Shapes (fixed): B=4, L=64, E=8, Q=16, K=32, H=512, NH=8, HD=64
// R16: attack R15's two offenders.
//  - proj_v2: whole-tile staging (16 upfront float4 loads/thread), ONE barrier,
//    barrier-free 16-step MFMA loop (R15 had 16 barriers + 1-deep prefetch).
//  - attn_mid: R15 attn_tail minus out-proj; x -> ws bf16 (aliases consumed qp).
//  - out_gemm: tiled GEMM for out = x@Wo + bo (Wo read once per 64-row block,
//    not once per 16 rows; R15 burned 1GB L2 on Wo re-reads).
// ws (proven >= 169,869,312 by R15): wt@0 2MB | qp@2M (x aliases) | kp@35.65M | vpT@102.76M.
// All MFMA lane mappings verbatim from R14/R15 (passed).

#define THREADS 512

typedef __attribute__((ext_vector_type(8))) short short8v;
typedef __attribute__((ext_vector_type(4))) short short4v;
typedef __attribute__((ext_vector_type(4))) float f32x4;

__device__ __forceinline__ short bf16b(float f) {
  __hip_bfloat16 h = __float2bfloat16(f);
  return *reinterpret_cast<short*>(&h);
}

// ---- W prep: wt[mat][n][k] = bf16(W[k][n]) ----
__global__ __launch_bounds__(256) void prep_w(const float* __restrict__ Wq,
                                              const float* __restrict__ Wk,
                                              const float* __restrict__ Wv,
                                              const float* __restrict__ Wo,
                                              short* __restrict__ wt) {
  __shared__ float tile[32][33];
  const int mat = blockIdx.x >> 8;
  const int tix = blockIdx.x & 255;
  const int n0 = (tix & 15) * 32, k0 = (tix >> 4) * 32;
  const float* W = (mat == 0) ? Wq : (mat == 1) ? Wk : (mat == 2) ? Wv : Wo;
  const int tx = threadIdx.x & 31, ty = threadIdx.x >> 5;
#pragma unroll
  for (int i = 0; i < 4; ++i)
    tile[ty + 8 * i][tx] = W[(size_t)(k0 + ty + 8 * i) * 512 + n0 + tx];
  __syncthreads();
#pragma unroll
  for (int i = 0; i < 4; ++i) {
    int n = ty + 8 * i, k = tx;
    wt[((size_t)(mat * 512 + n0 + n) << 9) + k0 + k] = bf16b(tile[k][n]);
  }
}

// ---- projection GEMM v2: 64 rows x 512 cols per block, one barrier ----
// MAT 0=Q(row-major, x0.125), 1=K(row-major), 2=V(transposed vpT[ble][n][key])
template <int MAT>
__global__ __launch_bounds__(THREADS, 4) void proj_v2(const float* __restrict__ A,
                                                      const float* __restrict__ bvec,
                                                      const short* __restrict__ wt,
                                                      short* __restrict__ C) {
  extern __shared__ char smem[];  // [64][520] bf16, stride 1040B
  const int t = threadIdx.x, lane = t & 63, w = t >> 6;
  const int lr = lane & 15, lo = lane >> 4;
  const int nw = w * 64;
  const int R0 = blockIdx.x * 64;
  const int srow = t >> 3, sc = (t & 7) << 2;

  // stage: 16 loads upfront (deep MLP), convert, write LDS
  float4 st[16];
#pragma unroll
  for (int c = 0; c < 16; ++c)
    st[c] = *(const float4*)&A[(size_t)(R0 + srow) * 512 + c * 32 + sc];
#pragma unroll
  for (int c = 0; c < 16; ++c) {
    short4v s4 = {bf16b(st[c].x), bf16b(st[c].y), bf16b(st[c].z), bf16b(st[c].w)};
    *(short4v*)(smem + srow * 1040 + (c * 32 + sc) * 2) = s4;
  }
  __syncthreads();

  f32x4 acc[4][4] = {};
#pragma unroll
  for (int ks = 0; ks < 16; ++ks) {
    short8v bfr[4];
#pragma unroll
    for (int nt = 0; nt < 4; ++nt)
      bfr[nt] = *(const short8v*)(wt + (((size_t)(MAT * 512 + nw + nt * 16 + lr)) << 9) +
                                  ks * 32 + lo * 8);
#pragma unroll
    for (int mt = 0; mt < 4; ++mt) {
      short8v a = *(const short8v*)(smem + (mt * 16 + lr) * 1040 + ks * 64 + lo * 16);
#pragma unroll
      for (int nt = 0; nt < 4; ++nt)
        acc[mt][nt] = __builtin_amdgcn_mfma_f32_16x16x32_bf16(a, bfr[nt], acc[mt][nt], 0, 0, 0);
    }
  }

#pragma unroll
  for (int nt = 0; nt < 4; ++nt) {
    int n = nw + nt * 16 + lr;
    float bb = bvec[n];
#pragma unroll
    for (int mt = 0; mt < 4; ++mt) {
      if (MAT == 2) {
        int rl0 = mt * 16 + lo * 4;
        int ble2 = (R0 + rl0) >> 5, key0 = rl0 & 31;
        short4v s4 = {bf16b(acc[mt][nt][0] + bb), bf16b(acc[mt][nt][1] + bb),
                      bf16b(acc[mt][nt][2] + bb), bf16b(acc[mt][nt][3] + bb)};
        *(short4v*)(C + (size_t)ble2 * 16384 + n * 32 + key0) = s4;
      } else {
#pragma unroll
        for (int r = 0; r < 4; ++r) {
          int rl = mt * 16 + lo * 4 + r;
          float v = acc[mt][nt][r] + bb;
          if (MAT == 0) {
            int ble2 = (R0 + rl) >> 4, q = rl & 15;
            C[(size_t)ble2 * 8192 + q * 512 + n] = bf16b(v * 0.125f);
          } else {
            int ble2 = (R0 + rl) >> 5, key = rl & 31;
            C[(size_t)ble2 * 16384 + key * 512 + n] = bf16b(v);
          }
        }
      }
    }
  }
}

// ---- attention mid: scores + softmax + top + PV -> x (bf16, aliases qp) ----
__global__ __launch_bounds__(THREADS, 4) void attn_mid(
    const short* __restrict__ qp, const short* __restrict__ kp, const short* __restrict__ vpT,
    const float* __restrict__ bias, short* __restrict__ xbuf, float* __restrict__ top) {
  extern __shared__ char smem[];  // p[8][16][40]s @0 (10240B) ; x[16][520]s @10240
  const int t = threadIdx.x, lane = t & 63, w = t >> 6;
  const int ble = blockIdx.x, e = ble & 7, bl = ble >> 3;
  const int lr = lane & 15, lo = lane >> 4;
  const int nw = w * 64;

  const short* qb = qp + (size_t)ble * 8192;
  const short* kb = kp + (size_t)ble * 16384;
  const short* vb = vpT + (size_t)ble * 16384;

  const float* brow = bias + (size_t)ble * 512;
  float bias8[8];
#pragma unroll
  for (int kt = 0; kt < 2; ++kt)
#pragma unroll
    for (int r = 0; r < 4; ++r)
      bias8[kt * 4 + r] = brow[(lo * 4 + r) * 32 + lr + 16 * kt];

  // scores (wave = head w)
  f32x4 sc[2] = {};
#pragma unroll
  for (int ks = 0; ks < 2; ++ks) {
    short8v aq = *(const short8v*)(qb + lr * 512 + nw + ks * 32 + lo * 8);
#pragma unroll
    for (int kt = 0; kt < 2; ++kt) {
      short8v b = *(const short8v*)(kb + (lr + 16 * kt) * 512 + nw + ks * 32 + lo * 8);
      sc[kt] = __builtin_amdgcn_mfma_f32_16x16x32_bf16(aq, b, sc[kt], 0, 0, 0);
    }
  }
  // softmax + p LDS + top
  float attn8[8];
  {
    float s8[8];
#pragma unroll
    for (int kt = 0; kt < 2; ++kt)
#pragma unroll
      for (int r = 0; r < 4; ++r) s8[kt * 4 + r] = sc[kt][r] + bias8[kt * 4 + r];
#pragma unroll
    for (int r = 0; r < 4; ++r) {
      float mx = fmaxf(s8[r], s8[4 + r]);
#pragma unroll
      for (int off = 1; off < 16; off <<= 1) mx = fmaxf(mx, __shfl_xor(mx, off, 16));
      float p0 = expf(s8[r] - mx), p1 = expf(s8[4 + r] - mx);
      float sm = p0 + p1;
#pragma unroll
      for (int off = 1; off < 16; off <<= 1) sm += __shfl_xor(sm, off, 16);
      float inv = 1.f / sm;
      attn8[r] = p0 * inv;
      attn8[4 + r] = p1 * inv;
    }
#pragma unroll
    for (int kt = 0; kt < 2; ++kt)
#pragma unroll
      for (int r = 0; r < 4; ++r) {
        int q = lo * 4 + r, key = lr + 16 * kt;
        *(short*)(smem + w * 1280 + q * 80 + key * 2) = bf16b(attn8[kt * 4 + r]);
        if (((w & 3) == 0) && lo < 2)
          top[(((size_t)bl * 16 + 2 * e + (w >> 2)) * 32 + 4 * q + (key >> 3)) * 8 + (key & 7)] =
              attn8[kt * 4 + r];
      }
  }

  // PV (wave-local p; no barrier needed before reads, as R14/R15)
  {
    f32x4 xacc[4] = {};
    short8v ap = *(const short8v*)(smem + w * 1280 + lr * 80 + lo * 16);
#pragma unroll
    for (int nt = 0; nt < 4; ++nt) {
      short8v b = *(const short8v*)(vb + (nw + nt * 16 + lr) * 32 + lo * 8);
      xacc[nt] = __builtin_amdgcn_mfma_f32_16x16x32_bf16(ap, b, xacc[nt], 0, 0, 0);
    }
#pragma unroll
    for (int nt = 0; nt < 4; ++nt)
#pragma unroll
      for (int r = 0; r < 4; ++r)
        *(short*)(smem + 10240 + (lo * 4 + r) * 1040 + (nw + nt * 16 + lr) * 2) =
            bf16b(xacc[nt][r]);
  }
  __syncthreads();

  // coalesced x copy-out (overwrites this ble's consumed qp region)
  {
    short* xg = xbuf + (size_t)ble * 8192;
    const int row = t >> 5, c0 = (t & 31) * 16;
    *(short8v*)(xg + row * 512 + c0) = *(const short8v*)(smem + 10240 + row * 1040 + c0 * 2);
    *(short8v*)(xg + row * 512 + c0 + 8) =
        *(const short8v*)(smem + 10240 + row * 1040 + (c0 + 8) * 2);
  }
}

// ---- out GEMM: out[32768][512] = x @ Wo + bo ----
__global__ __launch_bounds__(THREADS, 4) void out_gemm(const short* __restrict__ x,
                                                       const float* __restrict__ bo,
                                                       const short* __restrict__ wt,
                                                       float* __restrict__ out) {
  extern __shared__ char smem[];  // [64][520] bf16
  const int t = threadIdx.x, lane = t & 63, w = t >> 6;
  const int lr = lane & 15, lo = lane >> 4;
  const int nw = w * 64;
  const int R0 = blockIdx.x * 64;
  const int srow = t >> 3, scb = (t & 7) * 64;

#pragma unroll
  for (int j = 0; j < 8; ++j) {
    short8v v = *(const short8v*)(x + (size_t)(R0 + srow) * 512 + scb + j * 8);
    *(short8v*)(smem + srow * 1040 + (scb + j * 8) * 2) = v;
  }
  __syncthreads();

  f32x4 acc[4][4] = {};
#pragma unroll
  for (int ks = 0; ks < 16; ++ks) {
    short8v bfr[4];
#pragma unroll
    for (int nt = 0; nt < 4; ++nt)
      bfr[nt] = *(const short8v*)(wt + (((size_t)(1536 + nw + nt * 16 + lr)) << 9) + ks * 32 +
                                  lo * 8);
#pragma unroll
    for (int mt = 0; mt < 4; ++mt) {
      short8v a = *(const short8v*)(smem + (mt * 16 + lr) * 1040 + ks * 64 + lo * 16);
#pragma unroll
      for (int nt = 0; nt < 4; ++nt)
        acc[mt][nt] = __builtin_amdgcn_mfma_f32_16x16x32_bf16(a, bfr[nt], acc[mt][nt], 0, 0, 0);
    }
  }

#pragma unroll
  for (int nt = 0; nt < 4; ++nt) {
    int n = nw + nt * 16 + lr;
    float bb = bo[n];
#pragma unroll
    for (int mt = 0; mt < 4; ++mt)
#pragma unroll
      for (int r = 0; r < 4; ++r)
        out[(size_t)(R0 + mt * 16 + lo * 4 + r) * 512 + n] = acc[mt][nt][r] + bb;
  }
}

extern "C" void kernel_launch(void* const* d_in, const int* in_sizes, int n_in,
                              void* d_out, int out_size, void* d_ws, size_t ws_size,
                              hipStream_t stream) {
  const float* query = (const float*)d_in[0];
  const float* key_a = (const float*)d_in[1];
  const float* val_a = (const float*)d_in[2];
  const float* bias = (const float*)d_in[3];
  const float* Wq = (const float*)d_in[4];
  const float* bq = (const float*)d_in[5];
  const float* Wk = (const float*)d_in[6];
  const float* bk = (const float*)d_in[7];
  const float* Wv = (const float*)d_in[8];
  const float* bv = (const float*)d_in[9];
  const float* Wo = (const float*)d_in[10];
  const float* bo = (const float*)d_in[11];
  float* out = (float*)d_out;
  float* top = out + 16777216;

  short* wt = (short*)d_ws;
  short* qpw = (short*)((char*)d_ws + 2097152);   // x aliases this after attn_mid
  short* kpw = (short*)((char*)d_ws + 35651584);
  short* vpw = (short*)((char*)d_ws + 102760448);

  prep_w<<<1024, 256, 0, stream>>>(Wq, Wk, Wv, Wo, wt);
  proj_v2<0><<<512, THREADS, 66560, stream>>>(query, bq, wt, qpw);
  proj_v2<1><<<1024, THREADS, 66560, stream>>>(key_a, bk, wt, kpw);
  proj_v2<2><<<1024, THREADS, 66560, stream>>>(val_a, bv, wt, vpw);
  attn_mid<<<2048, THREADS, 26880, stream>>>(qpw, kpw, vpw, bias, qpw, top);
  out_gemm<<<512, THREADS, 66560, stream>>>(qpw, bo, wt, out);
}